// Round 1
// baseline (5762.749 us; speedup 1.0000x reference)
//
#include <hip/hip_runtime.h>

// ECGLSTM: B=256, T=5000, input_size=1, H=64, fused FC(64->128)+ReLU.
// R6: ONE WAVE (64 threads) per batch element. Lane u owns hidden unit u and
// computes ALL FOUR of its gates (4 W_hh rows = 256 VGPRs in registers).
// Consequences vs R5 (4 waves, 1 barrier/step):
//   - ZERO barriers in the whole kernel (single wave; same-wave LDS ops are
//     pipeline-ordered, same assumption R5 already made for its h buffers).
//   - The gates LDS round trip is gone (i,f,g,o are lane-local registers).
//   - Per-step LDS traffic: 16 b128 broadcast h-reads + 1 b32 x-read + 1 write
//     (was 4 waves x that, plus gate exchange).
//   - Per-step critical path = 128 pk_fma issue (256 cyc) + trans + one
//     h write->read round trip, instead of ~995 cyc of barrier+LDS latency.
// Arithmetic is bitwise-identical to R5 (same pair-wise pk-FMA reduction
// order per gate, same activation formulas) -> absmax should stay ~4e-6.

#define LSTM_H 64
#define LSTM_T 5000
#define LSTM_B 256

typedef float v2f __attribute__((ext_vector_type(2)));

__device__ __forceinline__ void pk_fma_acc(v2f& acc, v2f a, v2f b) {
    // acc = a*b + acc, accumulate in place (tied operand -> no v_mov)
    asm("v_pk_fma_f32 %0, %1, %2, %0" : "+v"(acc) : "v"(a), "v"(b));
}

__device__ __forceinline__ float fast_rcp(float v) {
    return __builtin_amdgcn_rcpf(v);
}

__global__ __launch_bounds__(64, 1) void ECGLSTM_lstm_1wave(
    const float* __restrict__ x,      // [B, T]
    const float* __restrict__ W_ih,   // [4H, 1]
    const float* __restrict__ W_hh,   // [4H, H]
    const float* __restrict__ b_ih,   // [4H]
    const float* __restrict__ b_hh,   // [4H]
    const float* __restrict__ W_fc,   // [128, H]
    const float* __restrict__ b_fc,   // [128]
    float* __restrict__ out)          // [B, 128]
{
    const int u = threadIdx.x;        // hidden unit 0..63
    const int b = blockIdx.x;

    __shared__ float xch[LSTM_T];     // whole x row, staged once (20 KB)
    __shared__ float hbuf[2][LSTM_H]; // double-buffered h (WAR safety)

    // Stage x (coalesced, once; same-wave ordering -> no barrier needed)
    const float* xb = x + b * LSTM_T;
    for (int i = u; i < LSTM_T; i += 64) xch[i] = xb[i];

    // All 4 W_hh rows for unit u -> 128 v2f = 256 VGPRs (L2-resident after
    // the first block touches them; one-time cost).
    v2f wi[LSTM_H / 2], wf[LSTM_H / 2], wg[LSTM_H / 2], wo[LSTM_H / 2];
    {
        const float4* ri = reinterpret_cast<const float4*>(W_hh + (0 * LSTM_H + u) * LSTM_H);
        const float4* rf = reinterpret_cast<const float4*>(W_hh + (1 * LSTM_H + u) * LSTM_H);
        const float4* rg = reinterpret_cast<const float4*>(W_hh + (2 * LSTM_H + u) * LSTM_H);
        const float4* ro = reinterpret_cast<const float4*>(W_hh + (3 * LSTM_H + u) * LSTM_H);
        #pragma unroll
        for (int i = 0; i < LSTM_H / 4; ++i) {
            float4 vi = ri[i], vf = rf[i], vg = rg[i], vo = ro[i];
            wi[2 * i] = v2f{vi.x, vi.y}; wi[2 * i + 1] = v2f{vi.z, vi.w};
            wf[2 * i] = v2f{vf.x, vf.y}; wf[2 * i + 1] = v2f{vf.z, vf.w};
            wg[2 * i] = v2f{vg.x, vg.y}; wg[2 * i + 1] = v2f{vg.z, vg.w};
            wo[2 * i] = v2f{vo.x, vo.y}; wo[2 * i + 1] = v2f{vo.z, vo.w};
        }
    }
    const float wih_i = W_ih[0 * LSTM_H + u];
    const float wih_f = W_ih[1 * LSTM_H + u];
    const float wih_g = W_ih[2 * LSTM_H + u];
    const float wih_o = W_ih[3 * LSTM_H + u];
    const float bias_i = b_ih[0 * LSTM_H + u] + b_hh[0 * LSTM_H + u];
    const float bias_f = b_ih[1 * LSTM_H + u] + b_hh[1 * LSTM_H + u];
    const float bias_g = b_ih[2 * LSTM_H + u] + b_hh[2 * LSTM_H + u];
    const float bias_o = b_ih[3 * LSTM_H + u] + b_hh[3 * LSTM_H + u];

    float c = 0.0f;
    hbuf[0][u] = 0.0f;                // same-wave write; ordered before reads

    // One LSTM step: read hbuf[P], write hbuf[1-P]. No barrier anywhere:
    // single wave, LDS pipeline processes this wave's ops in program order.
    #define LSTM_STEP(t, P)                                                    \
    {                                                                          \
        const float xv = xch[(t)];                      /* broadcast b32 */    \
        v2f Ai = {0.f,0.f}, Ci = {0.f,0.f};                                    \
        v2f Af = {0.f,0.f}, Cf = {0.f,0.f};                                    \
        v2f Ag = {0.f,0.f}, Cg = {0.f,0.f};                                    \
        v2f Ao = {0.f,0.f}, Co = {0.f,0.f};                                    \
        const float4* h4 = reinterpret_cast<const float4*>(hbuf[(P)]);         \
        _Pragma("unroll")                                                      \
        for (int i = 0; i < LSTM_H / 4; ++i) {                                 \
            float4 hv = h4[i];                          /* b128 broadcast */   \
            v2f hlo = v2f{hv.x, hv.y};                                         \
            v2f hhi = v2f{hv.z, hv.w};                                         \
            pk_fma_acc(Ai, hlo, wi[2 * i]); pk_fma_acc(Ci, hhi, wi[2 * i + 1]);\
            pk_fma_acc(Af, hlo, wf[2 * i]); pk_fma_acc(Cf, hhi, wf[2 * i + 1]);\
            pk_fma_acc(Ag, hlo, wg[2 * i]); pk_fma_acc(Cg, hhi, wg[2 * i + 1]);\
            pk_fma_acc(Ao, hlo, wo[2 * i]); pk_fma_acc(Co, hhi, wo[2 * i + 1]);\
        }                                                                      \
        float gi = fmaf(xv, wih_i, bias_i) + ((Ai.x + Ai.y) + (Ci.x + Ci.y));  \
        float gf = fmaf(xv, wih_f, bias_f) + ((Af.x + Af.y) + (Cf.x + Cf.y));  \
        float gg = fmaf(xv, wih_g, bias_g) + ((Ag.x + Ag.y) + (Cg.x + Cg.y));  \
        float go = fmaf(xv, wih_o, bias_o) + ((Ao.x + Ao.y) + (Co.x + Co.y));  \
        float ei = __expf(-gi);        float i_ = fast_rcp(1.0f + ei);         \
        float ef = __expf(-gf);        float f_ = fast_rcp(1.0f + ef);         \
        float eg = __expf(2.0f * gg);  float g_ = 1.0f - 2.0f * fast_rcp(eg + 1.0f); \
        float eo = __expf(-go);        float o_ = fast_rcp(1.0f + eo);         \
        c = fmaf(f_, c, i_ * g_);                                              \
        float e2 = __expf(2.0f * c);                                           \
        float th = 1.0f - 2.0f * fast_rcp(e2 + 1.0f);                          \
        hbuf[1 - (P)][u] = o_ * th;                                            \
    }

    for (int t = 0; t < LSTM_T; t += 2) {
        LSTM_STEP(t, 0);
        LSTM_STEP(t + 1, 1);
    }
    #undef LSTM_STEP

    // Final h is in hbuf[0] (T even). Same wave wrote it -> ordered reads.
    // FC(64->128)+ReLU: each lane computes rows u and u+64 (same fmaf order
    // as R5's epilogue for bitwise-identical results).
    float4 hreg[LSTM_H / 4];
    {
        const float4* h4 = reinterpret_cast<const float4*>(hbuf[0]);
        #pragma unroll
        for (int i = 0; i < LSTM_H / 4; ++i) hreg[i] = h4[i];
    }
    #pragma unroll
    for (int r0 = 0; r0 < 2; ++r0) {
        const int r = u + r0 * 64;
        float s = b_fc[r];
        const float4* wf4 = reinterpret_cast<const float4*>(W_fc + r * LSTM_H);
        #pragma unroll
        for (int i = 0; i < LSTM_H / 4; ++i) {
            float4 wv = wf4[i];
            float4 hv = hreg[i];
            s = fmaf(hv.x, wv.x, s);
            s = fmaf(hv.y, wv.y, s);
            s = fmaf(hv.z, wv.z, s);
            s = fmaf(hv.w, wv.w, s);
        }
        out[b * 128 + r] = fmaxf(s, 0.0f);
    }
}

extern "C" void kernel_launch(void* const* d_in, const int* in_sizes, int n_in,
                              void* d_out, int out_size, void* d_ws, size_t ws_size,
                              hipStream_t stream) {
    const float* x    = (const float*)d_in[0];
    const float* W_ih = (const float*)d_in[1];
    const float* W_hh = (const float*)d_in[2];
    const float* b_ih = (const float*)d_in[3];
    const float* b_hh = (const float*)d_in[4];
    const float* W_fc = (const float*)d_in[5];
    const float* b_fc = (const float*)d_in[6];
    float* out = (float*)d_out;

    ECGLSTM_lstm_1wave<<<LSTM_B, 64, 0, stream>>>(
        x, W_ih, W_hh, b_ih, b_hh, W_fc, b_fc, out);
}

// Round 2
// 1998.537 us; speedup vs baseline: 2.8835x; 2.8835x over previous
//
#include <hip/hip_runtime.h>

// ECGLSTM: B=256, T=5000, input_size=1, H=64, fused FC(64->128)+ReLU.
// R7: 4 waves/block, ONE block per batch element, lane = 4*u_local + gate.
//   - Wave w owns hidden units 16w..16w+15. Each lane computes ONE gate's
//     full-K dot (64 weights = 64 VGPRs -> no spill, unlike R6's 256-VGPR
//     arch-limit blowup, WRITE_SIZE 2304KB of scratch traffic).
//   - The 4 gates of a unit live in 4 ADJACENT LANES of the SAME wave ->
//     exchanged with 4 DPP quad_perm broadcasts (~10 cyc) instead of R5's
//     gate LDS round trip (write+barrier+read ~250 cyc).
//   - Branchless activation: act = fmaf(s, rcp(1+exp(a*g)), d) with per-lane
//     (a,s,d) = (-1,1,0) sigmoid / (-2,2,-1) tanh -> no quad divergence,
//     ONE exp chain for all lanes. fmaf(1,x,0)==x exactly, so sigmoid lanes
//     are bitwise-identical to R5.
//   - ONE __syncthreads per step (h exchange only), double-buffered hbuf.
//   - x row staged to LDS once: no global loads in the loop.

#define LSTM_H 64
#define LSTM_T 5000
#define LSTM_B 256

typedef float v2f __attribute__((ext_vector_type(2)));

__device__ __forceinline__ void pk_fma_acc(v2f& acc, v2f a, v2f b) {
    // acc = a*b + acc, accumulate in place (tied operand -> no v_mov)
    asm("v_pk_fma_f32 %0, %1, %2, %0" : "+v"(acc) : "v"(a), "v"(b));
}

__device__ __forceinline__ float fast_rcp(float v) {
    return __builtin_amdgcn_rcpf(v);
}

// Broadcast lane (quad_base + K)'s value to all 4 lanes of the quad (DPP).
template<int K>
__device__ __forceinline__ float quad_bcast(float v) {
    constexpr int ctrl = K | (K << 2) | (K << 4) | (K << 6);  // quad_perm
    int r = __builtin_amdgcn_mov_dpp(__builtin_bit_cast(int, v),
                                     ctrl, 0xf, 0xf, false);
    return __builtin_bit_cast(float, r);
}

__global__ __launch_bounds__(256) void ECGLSTM_lstm_quad(
    const float* __restrict__ x,      // [B, T]
    const float* __restrict__ W_ih,   // [4H, 1]
    const float* __restrict__ W_hh,   // [4H, H]
    const float* __restrict__ b_ih,   // [4H]
    const float* __restrict__ b_hh,   // [4H]
    const float* __restrict__ W_fc,   // [128, H]
    const float* __restrict__ b_fc,   // [128]
    float* __restrict__ out)          // [B, 128]
{
    const int tid  = threadIdx.x;     // 0..255
    const int lane = tid & 63;
    const int w    = tid >> 6;        // wave 0..3
    const int g    = lane & 3;        // gate: 0=i 1=f 2=g 3=o
    const int ul   = lane >> 2;       // unit-local 0..15
    const int u    = w * 16 + ul;     // hidden unit 0..63
    const int b    = blockIdx.x;

    __shared__ float xch[LSTM_T];     // whole x row, staged once (20 KB)
    __shared__ float hbuf[2][LSTM_H]; // double-buffered h

    // Stage x (coalesced, once)
    const float* xb = x + b * LSTM_T;
    for (int i = tid; i < LSTM_T; i += 256) xch[i] = xb[i];

    // W_hh row (g*64 + u) -> 32 v2f = 64 VGPRs
    const int row = g * LSTM_H + u;
    v2f wreg[LSTM_H / 2];
    {
        const float4* wrow = reinterpret_cast<const float4*>(W_hh + row * LSTM_H);
        #pragma unroll
        for (int i = 0; i < LSTM_H / 4; ++i) {
            float4 v = wrow[i];
            wreg[2 * i]     = v2f{v.x, v.y};
            wreg[2 * i + 1] = v2f{v.z, v.w};
        }
    }
    const float wih  = W_ih[row];
    const float bias = b_ih[row] + b_hh[row];
    const bool  is_t = (g == 2);                  // tanh gate
    const float aexp = is_t ? -2.0f : -1.0f;      // e = exp(aexp * gate)
    const float smul = is_t ?  2.0f :  1.0f;      // act = s*rcp(1+e) + d
    const float dadd = is_t ? -1.0f :  0.0f;

    float c = 0.0f;                   // cell state, replicated across the quad
    if (tid < LSTM_H) hbuf[0][tid] = 0.0f;
    __syncthreads();                  // x staged + h0 visible

    // One LSTM step: read hbuf[P], write hbuf[1-P], ONE barrier at the end.
    // WAR safety: step t-1's reads of hbuf[1-P] happen before its ending
    // barrier; step t's write to hbuf[1-P] happens after it.
    #define LSTM_STEP(t, P)                                                    \
    {                                                                          \
        const float xv = xch[(t)];                      /* broadcast b32 */    \
        v2f a0 = {0.f,0.f}, a1 = {0.f,0.f}, a2 = {0.f,0.f}, a3 = {0.f,0.f};    \
        const float4* h4 = reinterpret_cast<const float4*>(hbuf[(P)]);         \
        _Pragma("unroll")                                                      \
        for (int i = 0; i < LSTM_H / 4; i += 2) {                              \
            float4 hva = h4[i];                         /* b128 broadcast */   \
            float4 hvb = h4[i + 1];                                            \
            pk_fma_acc(a0, v2f{hva.x, hva.y}, wreg[2 * i]);                    \
            pk_fma_acc(a1, v2f{hva.z, hva.w}, wreg[2 * i + 1]);                \
            pk_fma_acc(a2, v2f{hvb.x, hvb.y}, wreg[2 * i + 2]);                \
            pk_fma_acc(a3, v2f{hvb.z, hvb.w}, wreg[2 * i + 3]);                \
        }                                                                      \
        float dot = ((a0.x + a0.y) + (a1.x + a1.y))                            \
                  + ((a2.x + a2.y) + (a3.x + a3.y));                           \
        float gv  = fmaf(xv, wih, bias) + dot;                                 \
        float e   = __expf(aexp * gv);                                         \
        float act = fmaf(smul, fast_rcp(1.0f + e), dadd);                      \
        float i_  = quad_bcast<0>(act);                                        \
        float f_  = quad_bcast<1>(act);                                        \
        float g_  = quad_bcast<2>(act);                                        \
        float o_  = quad_bcast<3>(act);                                        \
        c = fmaf(f_, c, i_ * g_);                                              \
        float e2 = __expf(2.0f * c);                                           \
        float th = 1.0f - 2.0f * fast_rcp(e2 + 1.0f);                          \
        if (g == 0) hbuf[1 - (P)][u] = o_ * th;         /* 1 writer/unit */    \
        __syncthreads();                                /* the ONE barrier */  \
    }

    for (int t = 0; t < LSTM_T; t += 2) {
        LSTM_STEP(t, 0);
        LSTM_STEP(t + 1, 1);
    }
    #undef LSTM_STEP

    // Final h is in hbuf[0] (T even); last step's barrier made it visible.
    // FC(64->128)+ReLU: threads 0..127 compute one output row each.
    if (tid < 128) {
        float s = b_fc[tid];
        const float4* wf = reinterpret_cast<const float4*>(W_fc + tid * LSTM_H);
        const float4* h4 = reinterpret_cast<const float4*>(hbuf[0]);
        #pragma unroll
        for (int i = 0; i < LSTM_H / 4; ++i) {
            float4 wv = wf[i];
            float4 hv = h4[i];
            s = fmaf(hv.x, wv.x, s);
            s = fmaf(hv.y, wv.y, s);
            s = fmaf(hv.z, wv.z, s);
            s = fmaf(hv.w, wv.w, s);
        }
        out[b * 128 + tid] = fmaxf(s, 0.0f);
    }
}

extern "C" void kernel_launch(void* const* d_in, const int* in_sizes, int n_in,
                              void* d_out, int out_size, void* d_ws, size_t ws_size,
                              hipStream_t stream) {
    const float* x    = (const float*)d_in[0];
    const float* W_ih = (const float*)d_in[1];
    const float* W_hh = (const float*)d_in[2];
    const float* b_ih = (const float*)d_in[3];
    const float* b_hh = (const float*)d_in[4];
    const float* W_fc = (const float*)d_in[5];
    const float* b_fc = (const float*)d_in[6];
    float* out = (float*)d_out;

    ECGLSTM_lstm_quad<<<LSTM_B, 256, 0, stream>>>(
        x, W_ih, W_hh, b_ih, b_hh, W_fc, b_fc, out);
}